// Round 1
// baseline (1742.169 us; speedup 1.0000x reference)
//
#include <hip/hip_runtime.h>

#define HDIM 256
#define PTS 8   // points per workgroup

__global__ __launch_bounds__(256, 2)
void pinn_phys_loss(const float* __restrict__ x_norm,
                    const float* __restrict__ nu,
                    const float* __restrict__ x_std,
                    const float* __restrict__ y_std,
                    const float* __restrict__ W0, const float* __restrict__ b0,
                    const float* __restrict__ W1, const float* __restrict__ b1,
                    const float* __restrict__ W2, const float* __restrict__ b2,
                    const float* __restrict__ W3, const float* __restrict__ b3,
                    const float* __restrict__ W4, const float* __restrict__ b4,
                    float* __restrict__ out, int npts)
{
    // activations for 8 points x 7 dual channels x 256 units (57344 B)
    __shared__ float a_s[PTS * 7 * HDIM];
    __shared__ float y_s[PTS * 6 * 4];   // final-layer derivative outputs

    const int tid  = threadIdx.x;
    const int jq   = tid & 63;        // thread owns units jq + {0,64,128,192}
    const int ph   = tid >> 6;        // 0..3 -> points {2ph, 2ph+1}
    const int p0   = ph * 2;
    const int base = blockIdx.x * PTS;

    // ----- layer 0: 3 -> 256, dual-number seed -----
    {
        float w[4][3], bb[4];
        #pragma unroll
        for (int h = 0; h < 4; ++h) {
            const int j = jq + 64*h;
            w[h][0] = W0[0*HDIM + j];
            w[h][1] = W0[1*HDIM + j];
            w[h][2] = W0[2*HDIM + j];
            bb[h]   = b0[j];
        }
        #pragma unroll
        for (int pp = 0; pp < 2; ++pp) {
            const int p  = p0 + pp;
            const int gp = base + p;
            const float x0 = x_norm[gp*3+0];
            const float x1 = x_norm[gp*3+1];
            const float x2 = x_norm[gp*3+2];
            #pragma unroll
            for (int h = 0; h < 4; ++h) {
                const int j = jq + 64*h;
                const float z = bb[h] + x0*w[h][0] + x1*w[h][1] + x2*w[h][2];
                const float t = tanhf(z);
                const float s = 1.f - t*t;
                a_s[(p*7+0)*HDIM + j] = t;
                #pragma unroll
                for (int i = 0; i < 3; ++i) {
                    const float d1 = w[h][i];               // dz/dx_i
                    a_s[(p*7+1+i)*HDIM + j] = s*d1;         // first deriv
                    a_s[(p*7+4+i)*HDIM + j] = -2.f*t*s*d1*d1; // second deriv
                }
            }
        }
    }
    __syncthreads();

    // ----- layers 1..3: 256 -> 256 on all 7 channels -----
    const float* Wmid[3] = {W1, W2, W3};
    const float* bmid[3] = {b1, b2, b3};
    #pragma unroll 1
    for (int L = 0; L < 3; ++L) {
        const float* __restrict__ W = Wmid[L];
        float acc[4][2][7];
        {
            const float* bl = bmid[L];
            #pragma unroll
            for (int h = 0; h < 4; ++h) {
                const float bj = bl[jq + 64*h];
                #pragma unroll
                for (int pp = 0; pp < 2; ++pp) {
                    acc[h][pp][0] = bj;      // bias only on value channel
                    #pragma unroll
                    for (int c = 1; c < 7; ++c) acc[h][pp][c] = 0.f;
                }
            }
        }
        for (int k = 0; k < HDIM; k += 4) {
            float w[4][4];
            #pragma unroll
            for (int s4 = 0; s4 < 4; ++s4) {
                #pragma unroll
                for (int h = 0; h < 4; ++h)
                    w[h][s4] = W[(k+s4)*HDIM + jq + 64*h];  // coalesced
            }
            #pragma unroll
            for (int pp = 0; pp < 2; ++pp) {
                #pragma unroll
                for (int c = 0; c < 7; ++c) {
                    // wave-uniform address -> LDS broadcast, conflict-free
                    const float4 av = *(const float4*)&a_s[((p0+pp)*7 + c)*HDIM + k];
                    #pragma unroll
                    for (int h = 0; h < 4; ++h)
                        acc[h][pp][c] += av.x*w[h][0] + av.y*w[h][1]
                                       + av.z*w[h][2] + av.w*w[h][3];
                }
            }
        }
        __syncthreads();   // all reads of a_s done
        #pragma unroll
        for (int h = 0; h < 4; ++h) {
            const int j = jq + 64*h;
            #pragma unroll
            for (int pp = 0; pp < 2; ++pp) {
                const int p = p0 + pp;
                const float t = tanhf(acc[h][pp][0]);
                const float s = 1.f - t*t;
                a_s[(p*7+0)*HDIM + j] = t;
                #pragma unroll
                for (int i = 0; i < 3; ++i) {
                    const float d1 = acc[h][pp][1+i];
                    const float d2 = acc[h][pp][4+i];
                    a_s[(p*7+1+i)*HDIM + j] = s*d1;
                    a_s[(p*7+4+i)*HDIM + j] = s*d2 - 2.f*t*s*d1*d1;
                }
            }
        }
        __syncthreads();
    }

    // ----- layer 4: 256 -> 4, derivative channels only (value unused) -----
    {
        const int pf = tid >> 5;      // 0..7 : point
        const int co = tid & 31;
        if (co < 24) {
            const int c6 = co >> 2;   // 0..5 : {d1_0..2, d2_0..2}
            const int oo = co & 3;    // output u,v,w,p
            const int ch = 1 + c6;    // channel index in a_s
            const int krot = co * 8;  // de-conflict rotation (bank spread)
            float dotv = 0.f;
            for (int kk = 0; kk < HDIM; kk += 4) {
                const int k = (kk + krot) & (HDIM-1);
                const float4 av = *(const float4*)&a_s[(pf*7+ch)*HDIM + k];
                dotv += av.x*W4[(k+0)*4+oo] + av.y*W4[(k+1)*4+oo]
                      + av.z*W4[(k+2)*4+oo] + av.w*W4[(k+3)*4+oo];
            }
            y_s[(pf*6 + c6)*4 + oo] = dotv;
        }
    }
    __syncthreads();

    // ----- per-point physics loss -----
    if (tid < PTS) {
        const int p = tid;
        const float xs0 = x_std[0], xs1 = x_std[1], xs2 = x_std[2];
        const float nuv = nu[0];
        float Js[4][3], Hs[4][3];
        #pragma unroll
        for (int o = 0; o < 4; ++o) {
            const float yo = y_std[o];
            Js[o][0] = y_s[(p*6+0)*4+o] * yo / xs0;
            Js[o][1] = y_s[(p*6+1)*4+o] * yo / xs1;
            Js[o][2] = y_s[(p*6+2)*4+o] * yo / xs2;
            Hs[o][0] = y_s[(p*6+3)*4+o] * yo / (xs0*xs0);
            Hs[o][1] = y_s[(p*6+4)*4+o] * yo / (xs1*xs1);
            Hs[o][2] = y_s[(p*6+5)*4+o] * yo / (xs2*xs2);
        }
        const float cont = Js[0][0] + Js[1][1] + Js[2][2];
        const float lap0 = Hs[0][0] + Hs[0][1] + Hs[0][2];
        const float lap1 = Hs[1][0] + Hs[1][1] + Hs[1][2];
        const float lap2 = Hs[2][0] + Hs[2][1] + Hs[2][2];
        const float mx = Js[3][0] - nuv*lap0;
        const float my = Js[3][1] - nuv*lap1;
        const float mz = Js[3][2] - nuv*lap2;
        out[base + p] = cont*cont + mx*mx + my*my + mz*mz;
    }
}

extern "C" void kernel_launch(void* const* d_in, const int* in_sizes, int n_in,
                              void* d_out, int out_size, void* d_ws, size_t ws_size,
                              hipStream_t stream)
{
    const float* x_norm = (const float*)d_in[0];
    const float* nu     = (const float*)d_in[1];
    const float* x_std  = (const float*)d_in[2];
    const float* y_std  = (const float*)d_in[3];
    const float* W0 = (const float*)d_in[4];  const float* b0 = (const float*)d_in[5];
    const float* W1 = (const float*)d_in[6];  const float* b1 = (const float*)d_in[7];
    const float* W2 = (const float*)d_in[8];  const float* b2 = (const float*)d_in[9];
    const float* W3 = (const float*)d_in[10]; const float* b3 = (const float*)d_in[11];
    const float* W4 = (const float*)d_in[12]; const float* b4 = (const float*)d_in[13];
    (void)b4; (void)d_ws; (void)ws_size; (void)n_in; (void)out_size;
    float* out = (float*)d_out;
    const int npts = in_sizes[0] / 3;
    const int nwg  = npts / PTS;
    pinn_phys_loss<<<nwg, 256, 0, stream>>>(x_norm, nu, x_std, y_std,
        W0, b0, W1, b1, W2, b2, W3, b3, W4, b4, out, npts);
}

// Round 3
// 338.352 us; speedup vs baseline: 5.1490x; 5.1490x over previous
//
#include <hip/hip_runtime.h>
#include <stdint.h>

typedef __attribute__((ext_vector_type(8))) short short8v;
typedef __attribute__((ext_vector_type(4))) float float4v;

#define NPTS_WG 16

// pack fp32 -> u32 [hi16 : lo16]: hi = truncated top-16, lo = bf16-bits of exact residual
__device__ __forceinline__ uint32_t pack_hilo(float x) {
    uint32_t xb = __float_as_uint(x);
    float hi = __uint_as_float(xb & 0xffff0000u);
    float r = x - hi;                       // exact
    uint32_t rb = __float_as_uint(r);
    return __builtin_amdgcn_perm(xb, rb, 0x07060302u);  // [xb.b3,xb.b2,rb.b3,rb.b2]
}

// swizzled LDS index for activation array A[c][p][k] (u32 elems, 256 per row).
// Swizzle operates on 16B slots (4 u32): slot' = slot ^ p. Any 16B access must
// compute its own a_idx (slots are NOT adjacent after XOR).
__device__ __forceinline__ int a_idx(int c, int p, int k) {
    return ((c * 16 + p) << 8) + ((((k >> 2) ^ p) << 2) | (k & 3));
}

// unpack 8 packed u32 (k = +0..+7) into hi/lo bf16x8 fragments
__device__ __forceinline__ void unpack_frags(const uint32_t* s, short8v& hi, short8v& lo) {
    union { uint32_t u[4]; short8v v; } H, L;
#pragma unroll
    for (int i = 0; i < 4; ++i) {
        H.u[i] = __builtin_amdgcn_perm(s[2 * i + 1], s[2 * i], 0x07060302u); // [hi(odd):hi(even)]
        L.u[i] = __builtin_amdgcn_perm(s[2 * i + 1], s[2 * i], 0x05040100u); // [lo(odd):lo(even)]
    }
    hi = H.v; lo = L.v;
}

// ---- precompute: transpose + hi/lo split W1..W3 into d_ws ----
// wt layout: [L][{hi,lo}][j][k] as ushort; hi at L*131072 + j*256 + k, lo at +65536
__global__ void wt_split_kernel(const float* __restrict__ W1, const float* __restrict__ W2,
                                const float* __restrict__ W3, unsigned short* __restrict__ wt)
{
    const int b = blockIdx.x;            // 48 blocks: 3 layers x 16 k-strips
    const int L = b >> 4;
    const int k0 = (b & 15) * 16;
    const float* W = (L == 0) ? W1 : (L == 1) ? W2 : W3;
    const int j = threadIdx.x;           // 0..255
    uint32_t hi[16], lo[16];
#pragma unroll
    for (int e = 0; e < 16; ++e) {
        const float x = W[(k0 + e) * 256 + j];     // coalesced: lanes = consecutive j
        const uint32_t xb = __float_as_uint(x);
        const float h = __uint_as_float(xb & 0xffff0000u);
        const float r = x - h;
        hi[e] = xb >> 16;
        lo[e] = __float_as_uint(r) >> 16;
    }
    unsigned short* dh = wt + (size_t)L * 131072 + j * 256 + k0;
    unsigned short* dl = dh + 65536;
    uint4 h0 = make_uint4(hi[0] | (hi[1] << 16), hi[2] | (hi[3] << 16),
                          hi[4] | (hi[5] << 16), hi[6] | (hi[7] << 16));
    uint4 h1 = make_uint4(hi[8] | (hi[9] << 16), hi[10] | (hi[11] << 16),
                          hi[12] | (hi[13] << 16), hi[14] | (hi[15] << 16));
    uint4 l0 = make_uint4(lo[0] | (lo[1] << 16), lo[2] | (lo[3] << 16),
                          lo[4] | (lo[5] << 16), lo[6] | (lo[7] << 16));
    uint4 l1 = make_uint4(lo[8] | (lo[9] << 16), lo[10] | (lo[11] << 16),
                          lo[12] | (lo[13] << 16), lo[14] | (lo[15] << 16));
    ((uint4*)dh)[0] = h0; ((uint4*)dh)[1] = h1;
    ((uint4*)dl)[0] = l0; ((uint4*)dl)[1] = l1;
}

// ---- main kernel: 512 threads (8 waves), 16 points per WG ----
__global__ __launch_bounds__(512, 2)
void pinn_mfma(const float* __restrict__ x_norm, const float* __restrict__ nu,
               const float* __restrict__ x_std, const float* __restrict__ y_std,
               const float* __restrict__ W0, const float* __restrict__ b0,
               const float* __restrict__ b1, const float* __restrict__ b2,
               const float* __restrict__ b3, const float* __restrict__ W4,
               const unsigned short* __restrict__ wt, float* __restrict__ out)
{
    __shared__ uint32_t A_lds[7 * 16 * 256];   // 114688 B packed hi/lo activations
    __shared__ float w4_lds[256 * 4];          // 4 KB
    __shared__ float part_lds[8 * 6 * 16 * 4]; // 12 KB split-K partials
    __shared__ float y_lds[24 * 16];           // 1.5 KB

    const int tid = threadIdx.x;
    const int lane = tid & 63;
    const int wv = tid >> 6;     // wave 0..7
    const int l15 = lane & 15;
    const int g = lane >> 4;     // 0..3
    const int base_pt = blockIdx.x * NPTS_WG;

    if (tid < 256) ((float4*)w4_lds)[tid] = ((const float4*)W4)[tid];

    // ---- layer 0: 3 -> 256 dual seed ----
    {
        const int p = tid >> 5;            // 0..15
        const int j8 = (tid & 31) * 8;
        const float x0 = x_norm[(base_pt + p) * 3 + 0];
        const float x1 = x_norm[(base_pt + p) * 3 + 1];
        const float x2 = x_norm[(base_pt + p) * 3 + 2];
        uint32_t packed[7][8];
#pragma unroll
        for (int e = 0; e < 8; ++e) {
            const int j = j8 + e;
            const float w0 = W0[0 * 256 + j];
            const float w1 = W0[1 * 256 + j];
            const float w2 = W0[2 * 256 + j];
            const float z = b0[j] + x0 * w0 + x1 * w1 + x2 * w2;
            const float t = tanhf(z);
            const float s = 1.f - t * t;
            packed[0][e] = pack_hilo(t);
            const float wvv[3] = {w0, w1, w2};
#pragma unroll
            for (int i = 0; i < 3; ++i) {
                packed[1 + i][e] = pack_hilo(s * wvv[i]);
                packed[4 + i][e] = pack_hilo(-2.f * t * s * wvv[i] * wvv[i]);
            }
        }
#pragma unroll
        for (int c = 0; c < 7; ++c) {
            // two independent 16B slots (swizzle is 16B-granular!)
            *(uint4*)&A_lds[a_idx(c, p, j8)] =
                make_uint4(packed[c][0], packed[c][1], packed[c][2], packed[c][3]);
            *(uint4*)&A_lds[a_idx(c, p, j8 + 4)] =
                make_uint4(packed[c][4], packed[c][5], packed[c][6], packed[c][7]);
        }
    }
    __syncthreads();

    // ---- layers 1..3: MFMA hi/lo 3-product ----
    const float* biases[3] = {b1, b2, b3};
#pragma unroll 1
    for (int L = 0; L < 3; ++L) {
        const unsigned short* wtL = wt + (size_t)L * 131072;
        float4v acc[7][2];
#pragma unroll
        for (int c = 0; c < 7; ++c)
#pragma unroll
            for (int jt = 0; jt < 2; ++jt) acc[c][jt] = (float4v){0.f, 0.f, 0.f, 0.f};

        for (int ks = 0; ks < 8; ++ks) {
            const int koct = ks * 32 + 8 * g;
            short8v bh[2], bl[2];
#pragma unroll
            for (int jt = 0; jt < 2; ++jt) {
                const int j = wv * 32 + jt * 16 + l15;
                bh[jt] = *(const short8v*)(wtL + j * 256 + koct);
                bl[jt] = *(const short8v*)(wtL + 65536 + j * 256 + koct);
            }
#pragma unroll
            for (int c = 0; c < 7; ++c) {
                uint32_t s[8];
                *(uint4*)&s[0] = *(const uint4*)&A_lds[a_idx(c, l15, koct)];
                *(uint4*)&s[4] = *(const uint4*)&A_lds[a_idx(c, l15, koct + 4)];
                short8v ah, al;
                unpack_frags(s, ah, al);
#pragma unroll
                for (int jt = 0; jt < 2; ++jt) {
                    acc[c][jt] = __builtin_amdgcn_mfma_f32_16x16x32_bf16(ah, bh[jt], acc[c][jt], 0, 0, 0);
                    acc[c][jt] = __builtin_amdgcn_mfma_f32_16x16x32_bf16(ah, bl[jt], acc[c][jt], 0, 0, 0);
                    acc[c][jt] = __builtin_amdgcn_mfma_f32_16x16x32_bf16(al, bh[jt], acc[c][jt], 0, 0, 0);
                }
            }
        }
        const float* bL = biases[L];
        const float bj0 = bL[wv * 32 + l15];
        const float bj1 = bL[wv * 32 + 16 + l15];
        __syncthreads();   // all reads of A done before overwrite
#pragma unroll
        for (int jt = 0; jt < 2; ++jt) {
            const int j = wv * 32 + jt * 16 + l15;
            const float bj = jt ? bj1 : bj0;
#pragma unroll
            for (int r = 0; r < 4; ++r) {
                const int p = 4 * g + r;
                const float z = acc[0][jt][r] + bj;
                const float t = tanhf(z);
                const float s = 1.f - t * t;
                A_lds[a_idx(0, p, j)] = pack_hilo(t);
#pragma unroll
                for (int i = 0; i < 3; ++i) {
                    const float d1 = acc[1 + i][jt][r];
                    const float d2 = acc[4 + i][jt][r];
                    A_lds[a_idx(1 + i, p, j)] = pack_hilo(s * d1);
                    A_lds[a_idx(4 + i, p, j)] = pack_hilo(s * d2 - 2.f * t * s * d1 * d1);
                }
            }
        }
        __syncthreads();
    }

    // ---- layer 4: 256 -> 4, split-K across waves (wave = k-slice) ----
    {
        const int koct = wv * 32 + 8 * g;
        union { uint32_t u[4]; short8v v; } HB, LB;
#pragma unroll
        for (int i = 0; i < 4; ++i) {
            const float w0v = (l15 < 4) ? w4_lds[(koct + 2 * i) * 4 + l15] : 0.f;
            const float w1v = (l15 < 4) ? w4_lds[(koct + 2 * i + 1) * 4 + l15] : 0.f;
            const uint32_t x0b = __float_as_uint(w0v);
            const uint32_t x1b = __float_as_uint(w1v);
            const float r0 = w0v - __uint_as_float(x0b & 0xffff0000u);
            const float r1 = w1v - __uint_as_float(x1b & 0xffff0000u);
            HB.u[i] = __builtin_amdgcn_perm(x1b, x0b, 0x07060302u);
            LB.u[i] = __builtin_amdgcn_perm(__float_as_uint(r1), __float_as_uint(r0), 0x07060302u);
        }
        float4v acc4[6];
#pragma unroll
        for (int c = 0; c < 6; ++c) acc4[c] = (float4v){0.f, 0.f, 0.f, 0.f};
#pragma unroll
        for (int c = 0; c < 6; ++c) {
            uint32_t s[8];
            *(uint4*)&s[0] = *(const uint4*)&A_lds[a_idx(1 + c, l15, koct)];
            *(uint4*)&s[4] = *(const uint4*)&A_lds[a_idx(1 + c, l15, koct + 4)];
            short8v ah, al;
            unpack_frags(s, ah, al);
            acc4[c] = __builtin_amdgcn_mfma_f32_16x16x32_bf16(ah, HB.v, acc4[c], 0, 0, 0);
            acc4[c] = __builtin_amdgcn_mfma_f32_16x16x32_bf16(ah, LB.v, acc4[c], 0, 0, 0);
            acc4[c] = __builtin_amdgcn_mfma_f32_16x16x32_bf16(al, HB.v, acc4[c], 0, 0, 0);
        }
        if (l15 < 4) {
#pragma unroll
            for (int c = 0; c < 6; ++c)
#pragma unroll
                for (int r = 0; r < 4; ++r)
                    part_lds[((wv * 6 + c) * 16 + (4 * g + r)) * 4 + l15] = acc4[c][r];
        }
    }
    __syncthreads();

    if (tid < 384) {          // reduce split-K partials + de-normalization scale
        const int p = tid & 15;
        const int co = tid >> 4;      // 0..23
        const int o = co & 3;
        const int c6 = co >> 2;       // 0..5: 0-2 = d1_i, 3-5 = d2_i
        float sum = 0.f;
#pragma unroll
        for (int w8 = 0; w8 < 8; ++w8) sum += part_lds[((w8 * 6 + c6) * 16 + p) * 4 + o];
        const int i = (c6 < 3) ? c6 : (c6 - 3);
        const float xs = x_std[i];
        const float scale = y_std[o] / ((c6 < 3) ? xs : (xs * xs));
        y_lds[co * 16 + p] = sum * scale;
    }
    __syncthreads();

    if (tid < 16) {           // physics loss per point
        const int p = tid;
        const float nuv = nu[0];
        #define YV(c6, o) y_lds[(((c6) * 4) + (o)) * 16 + p]
        const float cont = YV(0, 0) + YV(1, 1) + YV(2, 2);
        const float lap0 = YV(3, 0) + YV(4, 0) + YV(5, 0);
        const float lap1 = YV(3, 1) + YV(4, 1) + YV(5, 1);
        const float lap2 = YV(3, 2) + YV(4, 2) + YV(5, 2);
        const float mx = YV(0, 3) - nuv * lap0;
        const float my = YV(1, 3) - nuv * lap1;
        const float mz = YV(2, 3) - nuv * lap2;
        out[base_pt + p] = cont * cont + mx * mx + my * my + mz * mz;
        #undef YV
    }
}

extern "C" void kernel_launch(void* const* d_in, const int* in_sizes, int n_in,
                              void* d_out, int out_size, void* d_ws, size_t ws_size,
                              hipStream_t stream)
{
    const float* x_norm = (const float*)d_in[0];
    const float* nu     = (const float*)d_in[1];
    const float* x_std  = (const float*)d_in[2];
    const float* y_std  = (const float*)d_in[3];
    const float* W0 = (const float*)d_in[4];  const float* b0 = (const float*)d_in[5];
    const float* W1 = (const float*)d_in[6];  const float* b1 = (const float*)d_in[7];
    const float* W2 = (const float*)d_in[8];  const float* b2 = (const float*)d_in[9];
    const float* W3 = (const float*)d_in[10]; const float* b3 = (const float*)d_in[11];
    const float* W4 = (const float*)d_in[12];
    (void)n_in; (void)out_size; (void)ws_size;
    unsigned short* wt = (unsigned short*)d_ws;   // 786432 B
    float* out = (float*)d_out;
    const int npts = in_sizes[0] / 3;

    wt_split_kernel<<<48, 256, 0, stream>>>(W1, W2, W3, wt);
    pinn_mfma<<<npts / NPTS_WG, 512, 0, stream>>>(x_norm, nu, x_std, y_std,
        W0, b0, b1, b2, b3, W4, wt, out);
}

// Round 4
// 295.818 us; speedup vs baseline: 5.8893x; 1.1438x over previous
//
#include <hip/hip_runtime.h>
#include <stdint.h>

typedef __attribute__((ext_vector_type(8))) short short8v;
typedef __attribute__((ext_vector_type(4))) float float4v;

#define NPTS_WG 16

// u16-plane index for A[c][p][k]: row = 256 u16 = 32 16B-slots; slot ^= p.
// Any 16B-granule access computes its own index (slots not adjacent after XOR).
__device__ __forceinline__ int aidx16(int c, int p, int k) {
    return ((c * 16 + p) << 8) + ((((k >> 3) ^ p) << 3) | (k & 7));
}

// split fp32 -> (hi bf16-bits, lo bf16-bits of exact residual)
__device__ __forceinline__ void split16(float x, unsigned short& h, unsigned short& l) {
    const uint32_t xb = __float_as_uint(x);
    const float hi = __uint_as_float(xb & 0xffff0000u);
    h = (unsigned short)(xb >> 16);
    l = (unsigned short)(__float_as_uint(x - hi) >> 16);
}

__device__ __forceinline__ float fast_tanh(float z) {
    const float e = __expf(2.0f * z);        // v_exp_f32-based, ~2 ulp
    return 1.0f - 2.0f / (e + 1.0f);         // exact at saturation (inf -> 1)
}

// ---- precompute: transpose + hi/lo split W1..W3 into d_ws ----
// wt layout: [L][{hi,lo}][j][k] ushort; hi at L*131072 + j*256 + k, lo at +65536
__global__ void wt_split_kernel(const float* __restrict__ W1, const float* __restrict__ W2,
                                const float* __restrict__ W3, unsigned short* __restrict__ wt)
{
    const int b = blockIdx.x;            // 48 blocks: 3 layers x 16 k-strips
    const int L = b >> 4;
    const int k0 = (b & 15) * 16;
    const float* W = (L == 0) ? W1 : (L == 1) ? W2 : W3;
    const int j = threadIdx.x;           // 0..255
    uint32_t hi[16], lo[16];
#pragma unroll
    for (int e = 0; e < 16; ++e) {
        const float x = W[(k0 + e) * 256 + j];     // coalesced: lanes = consecutive j
        const uint32_t xb = __float_as_uint(x);
        const float h = __uint_as_float(xb & 0xffff0000u);
        const float r = x - h;
        hi[e] = xb >> 16;
        lo[e] = __float_as_uint(r) >> 16;
    }
    unsigned short* dh = wt + (size_t)L * 131072 + j * 256 + k0;
    unsigned short* dl = dh + 65536;
    uint4 h0 = make_uint4(hi[0] | (hi[1] << 16), hi[2] | (hi[3] << 16),
                          hi[4] | (hi[5] << 16), hi[6] | (hi[7] << 16));
    uint4 h1 = make_uint4(hi[8] | (hi[9] << 16), hi[10] | (hi[11] << 16),
                          hi[12] | (hi[13] << 16), hi[14] | (hi[15] << 16));
    uint4 l0 = make_uint4(lo[0] | (lo[1] << 16), lo[2] | (lo[3] << 16),
                          lo[4] | (lo[5] << 16), lo[6] | (lo[7] << 16));
    uint4 l1 = make_uint4(lo[8] | (lo[9] << 16), lo[10] | (lo[11] << 16),
                          lo[12] | (lo[13] << 16), lo[14] | (lo[15] << 16));
    ((uint4*)dh)[0] = h0; ((uint4*)dh)[1] = h1;
    ((uint4*)dl)[0] = l0; ((uint4*)dl)[1] = l1;
}

// ---- main kernel: 512 threads (8 waves), 16 points per WG ----
__global__ __launch_bounds__(512, 2)
void pinn_mfma(const float* __restrict__ x_norm, const float* __restrict__ nu,
               const float* __restrict__ x_std, const float* __restrict__ y_std,
               const float* __restrict__ W0, const float* __restrict__ b0,
               const float* __restrict__ b1, const float* __restrict__ b2,
               const float* __restrict__ b3, const float* __restrict__ W4,
               const unsigned short* __restrict__ wt, float* __restrict__ out)
{
    __shared__ unsigned short AH[7 * 16 * 256]; // 57344 B hi plane (fragment order)
    __shared__ unsigned short AL[7 * 16 * 256]; // 57344 B lo plane
    __shared__ float w4_lds[256 * 4];           // 4 KB
    __shared__ float part_lds[8 * 6 * 16 * 4];  // 12 KB split-K partials
    __shared__ float y_lds[24 * 16];            // 1.5 KB

    const int tid = threadIdx.x;
    const int lane = tid & 63;
    const int wv = tid >> 6;     // wave 0..7
    const int l15 = lane & 15;
    const int g = lane >> 4;     // 0..3
    const int base_pt = blockIdx.x * NPTS_WG;

    if (tid < 256) ((float4*)w4_lds)[tid] = ((const float4*)W4)[tid];

    // ---- layer 0: 3 -> 256 dual seed ----
    {
        const int p = tid >> 5;            // 0..15
        const int j8 = (tid & 31) * 8;
        const float x0 = x_norm[(base_pt + p) * 3 + 0];
        const float x1 = x_norm[(base_pt + p) * 3 + 1];
        const float x2 = x_norm[(base_pt + p) * 3 + 2];
        float w0r[8], w1r[8], w2r[8], b0r[8];
        *(float4*)&w0r[0] = *(const float4*)&W0[0 * 256 + j8];
        *(float4*)&w0r[4] = *(const float4*)&W0[0 * 256 + j8 + 4];
        *(float4*)&w1r[0] = *(const float4*)&W0[1 * 256 + j8];
        *(float4*)&w1r[4] = *(const float4*)&W0[1 * 256 + j8 + 4];
        *(float4*)&w2r[0] = *(const float4*)&W0[2 * 256 + j8];
        *(float4*)&w2r[4] = *(const float4*)&W0[2 * 256 + j8 + 4];
        *(float4*)&b0r[0] = *(const float4*)&b0[j8];
        *(float4*)&b0r[4] = *(const float4*)&b0[j8 + 4];
        union { unsigned short u[8]; short8v v; } hv[7], lv[7];
#pragma unroll
        for (int e = 0; e < 8; ++e) {
            const float z = b0r[e] + x0 * w0r[e] + x1 * w1r[e] + x2 * w2r[e];
            const float t = fast_tanh(z);
            const float s = 1.f - t * t;
            split16(t, hv[0].u[e], lv[0].u[e]);
            const float wvv[3] = {w0r[e], w1r[e], w2r[e]};
#pragma unroll
            for (int i = 0; i < 3; ++i) {
                split16(s * wvv[i], hv[1 + i].u[e], lv[1 + i].u[e]);
                split16(-2.f * t * s * wvv[i] * wvv[i], hv[4 + i].u[e], lv[4 + i].u[e]);
            }
        }
#pragma unroll
        for (int c = 0; c < 7; ++c) {
            const int ai = aidx16(c, p, j8);   // j8 is 8-aligned -> one 16B granule
            *(short8v*)&AH[ai] = hv[c].v;
            *(short8v*)&AL[ai] = lv[c].v;
        }
    }
    __syncthreads();

    // ---- layers 1..3: MFMA hi/lo 3-product, fragments read directly ----
    const float* biases[3] = {b1, b2, b3};
#pragma unroll 1
    for (int L = 0; L < 3; ++L) {
        const unsigned short* wtL = wt + (size_t)L * 131072;
        float4v acc[7][2];
#pragma unroll
        for (int c = 0; c < 7; ++c)
#pragma unroll
            for (int jt = 0; jt < 2; ++jt) acc[c][jt] = (float4v){0.f, 0.f, 0.f, 0.f};

        for (int ks = 0; ks < 8; ++ks) {
            const int koct = ks * 32 + 8 * g;
            short8v bh[2], bl[2];
#pragma unroll
            for (int jt = 0; jt < 2; ++jt) {
                const int j = wv * 32 + jt * 16 + l15;
                bh[jt] = *(const short8v*)(wtL + j * 256 + koct);
                bl[jt] = *(const short8v*)(wtL + 65536 + j * 256 + koct);
            }
#pragma unroll
            for (int c = 0; c < 7; ++c) {
                const int ai = aidx16(c, l15, koct);   // 16B granule
                const short8v ah = *(const short8v*)&AH[ai];
                const short8v al = *(const short8v*)&AL[ai];
#pragma unroll
                for (int jt = 0; jt < 2; ++jt) {
                    acc[c][jt] = __builtin_amdgcn_mfma_f32_16x16x32_bf16(ah, bh[jt], acc[c][jt], 0, 0, 0);
                    acc[c][jt] = __builtin_amdgcn_mfma_f32_16x16x32_bf16(ah, bl[jt], acc[c][jt], 0, 0, 0);
                    acc[c][jt] = __builtin_amdgcn_mfma_f32_16x16x32_bf16(al, bh[jt], acc[c][jt], 0, 0, 0);
                }
            }
        }
        const float* bL = biases[L];
        const float bj0 = bL[wv * 32 + l15];
        const float bj1 = bL[wv * 32 + 16 + l15];
        __syncthreads();   // all reads of A done before overwrite
#pragma unroll
        for (int jt = 0; jt < 2; ++jt) {
            const int j = wv * 32 + jt * 16 + l15;
            const float bj = jt ? bj1 : bj0;
#pragma unroll
            for (int r = 0; r < 4; ++r) {
                const int p = 4 * g + r;
                const int bidx = (p << 8) + ((((j >> 3) ^ p) << 3) | (j & 7)); // + c*4096
                const float z = acc[0][jt][r] + bj;
                const float t = fast_tanh(z);
                const float s = 1.f - t * t;
                unsigned short h, l;
                split16(t, h, l);
                AH[bidx] = h; AL[bidx] = l;
#pragma unroll
                for (int i = 0; i < 3; ++i) {
                    const float d1 = acc[1 + i][jt][r];
                    const float d2 = acc[4 + i][jt][r];
                    split16(s * d1, h, l);
                    AH[bidx + (1 + i) * 4096] = h; AL[bidx + (1 + i) * 4096] = l;
                    split16(s * d2 - 2.f * t * s * d1 * d1, h, l);
                    AH[bidx + (4 + i) * 4096] = h; AL[bidx + (4 + i) * 4096] = l;
                }
            }
        }
        __syncthreads();
    }

    // ---- layer 4: 256 -> 4, split-K across waves (wave = k-slice) ----
    {
        const int koct = wv * 32 + 8 * g;
        union { uint32_t u[4]; short8v v; } HB, LB;
#pragma unroll
        for (int i = 0; i < 4; ++i) {
            const float w0v = (l15 < 4) ? w4_lds[(koct + 2 * i) * 4 + l15] : 0.f;
            const float w1v = (l15 < 4) ? w4_lds[(koct + 2 * i + 1) * 4 + l15] : 0.f;
            const uint32_t x0b = __float_as_uint(w0v);
            const uint32_t x1b = __float_as_uint(w1v);
            const float r0 = w0v - __uint_as_float(x0b & 0xffff0000u);
            const float r1 = w1v - __uint_as_float(x1b & 0xffff0000u);
            HB.u[i] = __builtin_amdgcn_perm(x1b, x0b, 0x07060302u);
            LB.u[i] = __builtin_amdgcn_perm(__float_as_uint(r1), __float_as_uint(r0), 0x07060302u);
        }
        float4v acc4[6];
#pragma unroll
        for (int c = 0; c < 6; ++c) acc4[c] = (float4v){0.f, 0.f, 0.f, 0.f};
#pragma unroll
        for (int c = 0; c < 6; ++c) {
            const int ai = aidx16(1 + c, l15, koct);
            const short8v ah = *(const short8v*)&AH[ai];
            const short8v al = *(const short8v*)&AL[ai];
            acc4[c] = __builtin_amdgcn_mfma_f32_16x16x32_bf16(ah, HB.v, acc4[c], 0, 0, 0);
            acc4[c] = __builtin_amdgcn_mfma_f32_16x16x32_bf16(ah, LB.v, acc4[c], 0, 0, 0);
            acc4[c] = __builtin_amdgcn_mfma_f32_16x16x32_bf16(al, HB.v, acc4[c], 0, 0, 0);
        }
        if (l15 < 4) {
#pragma unroll
            for (int c = 0; c < 6; ++c)
#pragma unroll
                for (int r = 0; r < 4; ++r)
                    part_lds[((wv * 6 + c) * 16 + (4 * g + r)) * 4 + l15] = acc4[c][r];
        }
    }
    __syncthreads();

    if (tid < 384) {          // reduce split-K partials + de-normalization scale
        const int p = tid & 15;
        const int co = tid >> 4;      // 0..23
        const int o = co & 3;
        const int c6 = co >> 2;       // 0..5: 0-2 = d1_i, 3-5 = d2_i
        float sum = 0.f;
#pragma unroll
        for (int w8 = 0; w8 < 8; ++w8) sum += part_lds[((w8 * 6 + c6) * 16 + p) * 4 + o];
        const int i = (c6 < 3) ? c6 : (c6 - 3);
        const float xs = x_std[i];
        const float scale = y_std[o] / ((c6 < 3) ? xs : (xs * xs));
        y_lds[co * 16 + p] = sum * scale;
    }
    __syncthreads();

    if (tid < 16) {           // physics loss per point
        const int p = tid;
        const float nuv = nu[0];
        #define YV(c6, o) y_lds[(((c6) * 4) + (o)) * 16 + p]
        const float cont = YV(0, 0) + YV(1, 1) + YV(2, 2);
        const float lap0 = YV(3, 0) + YV(4, 0) + YV(5, 0);
        const float lap1 = YV(3, 1) + YV(4, 1) + YV(5, 1);
        const float lap2 = YV(3, 2) + YV(4, 2) + YV(5, 2);
        const float mx = YV(0, 3) - nuv * lap0;
        const float my = YV(1, 3) - nuv * lap1;
        const float mz = YV(2, 3) - nuv * lap2;
        out[base_pt + p] = cont * cont + mx * mx + my * my + mz * mz;
        #undef YV
    }
}

extern "C" void kernel_launch(void* const* d_in, const int* in_sizes, int n_in,
                              void* d_out, int out_size, void* d_ws, size_t ws_size,
                              hipStream_t stream)
{
    const float* x_norm = (const float*)d_in[0];
    const float* nu     = (const float*)d_in[1];
    const float* x_std  = (const float*)d_in[2];
    const float* y_std  = (const float*)d_in[3];
    const float* W0 = (const float*)d_in[4];  const float* b0 = (const float*)d_in[5];
    const float* W1 = (const float*)d_in[6];  const float* b1 = (const float*)d_in[7];
    const float* W2 = (const float*)d_in[8];  const float* b2 = (const float*)d_in[9];
    const float* W3 = (const float*)d_in[10]; const float* b3 = (const float*)d_in[11];
    const float* W4 = (const float*)d_in[12];
    (void)n_in; (void)out_size; (void)ws_size;
    unsigned short* wt = (unsigned short*)d_ws;   // 786432 B
    float* out = (float*)d_out;
    const int npts = in_sizes[0] / 3;

    wt_split_kernel<<<48, 256, 0, stream>>>(W1, W2, W3, wt);
    pinn_mfma<<<npts / NPTS_WG, 512, 0, stream>>>(x_norm, nu, x_std, y_std,
        W0, b0, b1, b2, b3, W4, wt, out);
}

// Round 5
// 223.044 us; speedup vs baseline: 7.8109x; 1.3263x over previous
//
#include <hip/hip_runtime.h>
#include <stdint.h>

typedef __attribute__((ext_vector_type(8))) _Float16 half8v;
typedef __attribute__((ext_vector_type(4))) float float4v;

#define NPTS_WG 16

// u16-plane index for A[c][p][k]: row = 256 u16 = 32 16B-slots; slot ^= p.
// Any 16B-granule access computes its own index (slots not adjacent after XOR).
__device__ __forceinline__ int aidx16(int c, int p, int k) {
    return ((c * 16 + p) << 8) + ((((k >> 3) ^ p) << 3) | (k & 7));
}

__device__ __forceinline__ unsigned short f16b(float x) {
    const _Float16 h = (_Float16)x;            // RN, 11-bit mantissa
    return __builtin_bit_cast(unsigned short, h);
}

__device__ __forceinline__ float fast_tanh(float z) {
    const float e = __expf(2.0f * z);          // ~2 ulp
    return 1.0f - 2.0f / (e + 1.0f);           // exact saturation
}

// ---- precompute: transpose + f16 hi/lo split W1..W3 into d_ws ----
// wt layout: [L][{hi,lo}][j][k] ushort(f16 bits); hi at L*131072 + j*256 + k, lo +65536
__global__ void wt_split_kernel(const float* __restrict__ W1, const float* __restrict__ W2,
                                const float* __restrict__ W3, unsigned short* __restrict__ wt)
{
    const int b = blockIdx.x;            // 48 blocks: 3 layers x 16 k-strips
    const int L = b >> 4;
    const int k0 = (b & 15) * 16;
    const float* W = (L == 0) ? W1 : (L == 1) ? W2 : W3;
    const int j = threadIdx.x;           // 0..255
    uint32_t hi[16], lo[16];
#pragma unroll
    for (int e = 0; e < 16; ++e) {
        const float x = W[(k0 + e) * 256 + j];     // coalesced: lanes = consecutive j
        const unsigned short h = f16b(x);
        const float hf = (float)__builtin_bit_cast(_Float16, h);
        hi[e] = h;
        lo[e] = f16b(x - hf);
    }
    unsigned short* dh = wt + (size_t)L * 131072 + j * 256 + k0;
    unsigned short* dl = dh + 65536;
    uint4 h0 = make_uint4(hi[0] | (hi[1] << 16), hi[2] | (hi[3] << 16),
                          hi[4] | (hi[5] << 16), hi[6] | (hi[7] << 16));
    uint4 h1 = make_uint4(hi[8] | (hi[9] << 16), hi[10] | (hi[11] << 16),
                          hi[12] | (hi[13] << 16), hi[14] | (hi[15] << 16));
    uint4 l0 = make_uint4(lo[0] | (lo[1] << 16), lo[2] | (lo[3] << 16),
                          lo[4] | (lo[5] << 16), lo[6] | (lo[7] << 16));
    uint4 l1 = make_uint4(lo[8] | (lo[9] << 16), lo[10] | (lo[11] << 16),
                          lo[12] | (lo[13] << 16), lo[14] | (lo[15] << 16));
    ((uint4*)dh)[0] = h0; ((uint4*)dh)[1] = h1;
    ((uint4*)dl)[0] = l0; ((uint4*)dl)[1] = l1;
}

// ---- main kernel: 512 threads (8 waves), 16 points per WG, 2 WG/CU ----
__global__ __launch_bounds__(512, 4)
void pinn_mfma(const float* __restrict__ x_norm, const float* __restrict__ nu,
               const float* __restrict__ x_std, const float* __restrict__ y_std,
               const float* __restrict__ W0, const float* __restrict__ b0,
               const float* __restrict__ b1, const float* __restrict__ b2,
               const float* __restrict__ b3, const float* __restrict__ W4,
               const unsigned short* __restrict__ wt, float* __restrict__ out)
{
    __shared__ unsigned short AH[7 * 16 * 256]; // 57344 B f16 activations (fragment order)
    __shared__ float w4_lds[256 * 4];           // 4 KB
    __shared__ float part_lds[8 * 6 * 16 * 4];  // 12 KB split-K partials
    __shared__ float y_lds[24 * 16];            // 1.5 KB

    const int tid = threadIdx.x;
    const int lane = tid & 63;
    const int wv = tid >> 6;     // wave 0..7
    const int l15 = lane & 15;
    const int g = lane >> 4;     // 0..3
    const int base_pt = blockIdx.x * NPTS_WG;

    if (tid < 256) ((float4*)w4_lds)[tid] = ((const float4*)W4)[tid];

    // ---- layer 0: 3 -> 256 dual seed ----
    {
        const int p = tid >> 5;            // 0..15
        const int j8 = (tid & 31) * 8;
        const float x0 = x_norm[(base_pt + p) * 3 + 0];
        const float x1 = x_norm[(base_pt + p) * 3 + 1];
        const float x2 = x_norm[(base_pt + p) * 3 + 2];
        float w0r[8], w1r[8], w2r[8], b0r[8];
        *(float4*)&w0r[0] = *(const float4*)&W0[0 * 256 + j8];
        *(float4*)&w0r[4] = *(const float4*)&W0[0 * 256 + j8 + 4];
        *(float4*)&w1r[0] = *(const float4*)&W0[1 * 256 + j8];
        *(float4*)&w1r[4] = *(const float4*)&W0[1 * 256 + j8 + 4];
        *(float4*)&w2r[0] = *(const float4*)&W0[2 * 256 + j8];
        *(float4*)&w2r[4] = *(const float4*)&W0[2 * 256 + j8 + 4];
        *(float4*)&b0r[0] = *(const float4*)&b0[j8];
        *(float4*)&b0r[4] = *(const float4*)&b0[j8 + 4];
        union { unsigned short u[8]; half8v v; } hv[7];
#pragma unroll
        for (int e = 0; e < 8; ++e) {
            const float z = b0r[e] + x0 * w0r[e] + x1 * w1r[e] + x2 * w2r[e];
            const float t = fast_tanh(z);
            const float s = 1.f - t * t;
            hv[0].u[e] = f16b(t);
            const float wvv[3] = {w0r[e], w1r[e], w2r[e]};
#pragma unroll
            for (int i = 0; i < 3; ++i) {
                hv[1 + i].u[e] = f16b(s * wvv[i]);
                hv[4 + i].u[e] = f16b(-2.f * t * s * wvv[i] * wvv[i]);
            }
        }
#pragma unroll
        for (int c = 0; c < 7; ++c)
            *(half8v*)&AH[aidx16(c, p, j8)] = hv[c].v;  // j8 8-aligned: one granule
    }
    __syncthreads();

    // ---- layers 1..3: MFMA 2-product (a_h*w_h + a_h*w_l), fragments direct ----
    const float* biases[3] = {b1, b2, b3};
#pragma unroll 1
    for (int L = 0; L < 3; ++L) {
        const unsigned short* wtL = wt + (size_t)L * 131072;
        float4v acc[7][2];
#pragma unroll
        for (int c = 0; c < 7; ++c)
#pragma unroll
            for (int jt = 0; jt < 2; ++jt) acc[c][jt] = (float4v){0.f, 0.f, 0.f, 0.f};

        for (int ks = 0; ks < 8; ++ks) {
            const int koct = ks * 32 + 8 * g;
            half8v bh[2], bl[2];
#pragma unroll
            for (int jt = 0; jt < 2; ++jt) {
                const int j = wv * 32 + jt * 16 + l15;
                bh[jt] = *(const half8v*)(wtL + j * 256 + koct);
                bl[jt] = *(const half8v*)(wtL + 65536 + j * 256 + koct);
            }
#pragma unroll
            for (int c = 0; c < 7; ++c) {
                const half8v ah = *(const half8v*)&AH[aidx16(c, l15, koct)];
#pragma unroll
                for (int jt = 0; jt < 2; ++jt) {
                    acc[c][jt] = __builtin_amdgcn_mfma_f32_16x16x32_f16(ah, bh[jt], acc[c][jt], 0, 0, 0);
                    acc[c][jt] = __builtin_amdgcn_mfma_f32_16x16x32_f16(ah, bl[jt], acc[c][jt], 0, 0, 0);
                }
            }
        }
        const float* bL = biases[L];
        const float bj0 = bL[wv * 32 + l15];
        const float bj1 = bL[wv * 32 + 16 + l15];
        __syncthreads();   // all reads of A done before overwrite
#pragma unroll
        for (int jt = 0; jt < 2; ++jt) {
            const int j = wv * 32 + jt * 16 + l15;
            const float bj = jt ? bj1 : bj0;
#pragma unroll
            for (int r = 0; r < 4; ++r) {
                const int p = 4 * g + r;
                const int bidx = (p << 8) + ((((j >> 3) ^ p) << 3) | (j & 7)); // + c*4096
                const float z = acc[0][jt][r] + bj;
                const float t = fast_tanh(z);
                const float s = 1.f - t * t;
                AH[bidx] = f16b(t);
#pragma unroll
                for (int i = 0; i < 3; ++i) {
                    const float d1 = acc[1 + i][jt][r];
                    const float d2 = acc[4 + i][jt][r];
                    AH[bidx + (1 + i) * 4096] = f16b(s * d1);
                    AH[bidx + (4 + i) * 4096] = f16b(s * d2 - 2.f * t * s * d1 * d1);
                }
            }
        }
        __syncthreads();
    }

    // ---- layer 4: 256 -> 4, split-K across waves (wave = k-slice) ----
    {
        const int koct = wv * 32 + 8 * g;
        union { uint32_t u[4]; half8v v; } HB, LB;
#pragma unroll
        for (int i = 0; i < 4; ++i) {
            const float w0v = (l15 < 4) ? w4_lds[(koct + 2 * i) * 4 + l15] : 0.f;
            const float w1v = (l15 < 4) ? w4_lds[(koct + 2 * i + 1) * 4 + l15] : 0.f;
            const unsigned short h0 = f16b(w0v), h1 = f16b(w1v);
            const float r0 = w0v - (float)__builtin_bit_cast(_Float16, h0);
            const float r1 = w1v - (float)__builtin_bit_cast(_Float16, h1);
            HB.u[i] = (uint32_t)h0 | ((uint32_t)h1 << 16);
            LB.u[i] = (uint32_t)f16b(r0) | ((uint32_t)f16b(r1) << 16);
        }
        float4v acc4[6];
#pragma unroll
        for (int c = 0; c < 6; ++c) acc4[c] = (float4v){0.f, 0.f, 0.f, 0.f};
#pragma unroll
        for (int c = 0; c < 6; ++c) {
            const half8v ah = *(const half8v*)&AH[aidx16(1 + c, l15, koct)];
            acc4[c] = __builtin_amdgcn_mfma_f32_16x16x32_f16(ah, HB.v, acc4[c], 0, 0, 0);
            acc4[c] = __builtin_amdgcn_mfma_f32_16x16x32_f16(ah, LB.v, acc4[c], 0, 0, 0);
        }
        if (l15 < 4) {
#pragma unroll
            for (int c = 0; c < 6; ++c)
#pragma unroll
                for (int r = 0; r < 4; ++r)
                    part_lds[((wv * 6 + c) * 16 + (4 * g + r)) * 4 + l15] = acc4[c][r];
        }
    }
    __syncthreads();

    if (tid < 384) {          // reduce split-K partials + de-normalization scale
        const int p = tid & 15;
        const int co = tid >> 4;      // 0..23
        const int o = co & 3;
        const int c6 = co >> 2;       // 0..5: 0-2 = d1_i, 3-5 = d2_i
        float sum = 0.f;
#pragma unroll
        for (int w8 = 0; w8 < 8; ++w8) sum += part_lds[((w8 * 6 + c6) * 16 + p) * 4 + o];
        const int i = (c6 < 3) ? c6 : (c6 - 3);
        const float xs = x_std[i];
        const float scale = y_std[o] / ((c6 < 3) ? xs : (xs * xs));
        y_lds[co * 16 + p] = sum * scale;
    }
    __syncthreads();

    if (tid < 16) {           // physics loss per point
        const int p = tid;
        const float nuv = nu[0];
        #define YV(c6, o) y_lds[(((c6) * 4) + (o)) * 16 + p]
        const float cont = YV(0, 0) + YV(1, 1) + YV(2, 2);
        const float lap0 = YV(3, 0) + YV(4, 0) + YV(5, 0);
        const float lap1 = YV(3, 1) + YV(4, 1) + YV(5, 1);
        const float lap2 = YV(3, 2) + YV(4, 2) + YV(5, 2);
        const float mx = YV(0, 3) - nuv * lap0;
        const float my = YV(1, 3) - nuv * lap1;
        const float mz = YV(2, 3) - nuv * lap2;
        out[base_pt + p] = cont * cont + mx * mx + my * my + mz * mz;
        #undef YV
    }
}

extern "C" void kernel_launch(void* const* d_in, const int* in_sizes, int n_in,
                              void* d_out, int out_size, void* d_ws, size_t ws_size,
                              hipStream_t stream)
{
    const float* x_norm = (const float*)d_in[0];
    const float* nu     = (const float*)d_in[1];
    const float* x_std  = (const float*)d_in[2];
    const float* y_std  = (const float*)d_in[3];
    const float* W0 = (const float*)d_in[4];  const float* b0 = (const float*)d_in[5];
    const float* W1 = (const float*)d_in[6];  const float* b1 = (const float*)d_in[7];
    const float* W2 = (const float*)d_in[8];  const float* b2 = (const float*)d_in[9];
    const float* W3 = (const float*)d_in[10]; const float* b3 = (const float*)d_in[11];
    const float* W4 = (const float*)d_in[12];
    (void)n_in; (void)out_size; (void)ws_size;
    unsigned short* wt = (unsigned short*)d_ws;   // 786432 B
    float* out = (float*)d_out;
    const int npts = in_sizes[0] / 3;

    wt_split_kernel<<<48, 256, 0, stream>>>(W1, W2, W3, wt);
    pinn_mfma<<<npts / NPTS_WG, 512, 0, stream>>>(x_norm, nu, x_std, y_std,
        W0, b0, b1, b2, b3, W4, wt, out);
}

// Round 6
// 214.747 us; speedup vs baseline: 8.1127x; 1.0386x over previous
//
#include <hip/hip_runtime.h>
#include <stdint.h>

typedef __attribute__((ext_vector_type(8))) _Float16 half8v;
typedef __attribute__((ext_vector_type(4))) float float4v;

#define NPTS_WG 16

// u16-plane index for A[c][p][k]: row = 256 u16 = 32 8-elem granules; granule ^= p.
// Any access computes its own granule (granules not adjacent after XOR).
__device__ __forceinline__ int aidx16(int c, int p, int k) {
    return ((c * 16 + p) << 8) + ((((k >> 3) ^ p) << 3) | (k & 7));
}

__device__ __forceinline__ unsigned short f16b(float x) {
    const _Float16 h = (_Float16)x;            // RN, 11-bit mantissa
    return __builtin_bit_cast(unsigned short, h);
}

__device__ __forceinline__ uint32_t pk2f16(float a, float b) {
    return (uint32_t)f16b(a) | ((uint32_t)f16b(b) << 16);
}

__device__ __forceinline__ float fast_tanh(float z) {
    const float e = __expf(2.0f * z);          // ~2 ulp
    return 1.0f - 2.0f / (e + 1.0f);           // exact saturation
}

// ---- precompute: transpose + f16 hi/lo split W1..W3 into d_ws ----
// wt layout: [L][{hi,lo}][j][k] ushort(f16 bits); hi at L*131072 + j*256 + k, lo +65536
__global__ void wt_split_kernel(const float* __restrict__ W1, const float* __restrict__ W2,
                                const float* __restrict__ W3, unsigned short* __restrict__ wt)
{
    const int b = blockIdx.x;            // 48 blocks: 3 layers x 16 k-strips
    const int L = b >> 4;
    const int k0 = (b & 15) * 16;
    const float* W = (L == 0) ? W1 : (L == 1) ? W2 : W3;
    const int j = threadIdx.x;           // 0..255
    uint32_t hi[16], lo[16];
#pragma unroll
    for (int e = 0; e < 16; ++e) {
        const float x = W[(k0 + e) * 256 + j];     // coalesced: lanes = consecutive j
        const unsigned short h = f16b(x);
        const float hf = (float)__builtin_bit_cast(_Float16, h);
        hi[e] = h;
        lo[e] = f16b(x - hf);
    }
    unsigned short* dh = wt + (size_t)L * 131072 + j * 256 + k0;
    unsigned short* dl = dh + 65536;
    uint4 h0 = make_uint4(hi[0] | (hi[1] << 16), hi[2] | (hi[3] << 16),
                          hi[4] | (hi[5] << 16), hi[6] | (hi[7] << 16));
    uint4 h1 = make_uint4(hi[8] | (hi[9] << 16), hi[10] | (hi[11] << 16),
                          hi[12] | (hi[13] << 16), hi[14] | (hi[15] << 16));
    uint4 l0 = make_uint4(lo[0] | (lo[1] << 16), lo[2] | (lo[3] << 16),
                          lo[4] | (lo[5] << 16), lo[6] | (lo[7] << 16));
    uint4 l1 = make_uint4(lo[8] | (lo[9] << 16), lo[10] | (lo[11] << 16),
                          lo[12] | (lo[13] << 16), lo[14] | (lo[15] << 16));
    ((uint4*)dh)[0] = h0; ((uint4*)dh)[1] = h1;
    ((uint4*)dl)[0] = l0; ((uint4*)dl)[1] = l1;
}

// ---- main kernel: 512 threads (8 waves), 16 points per WG, 2 WG/CU ----
__global__ __launch_bounds__(512, 4)
void pinn_mfma(const float* __restrict__ x_norm, const float* __restrict__ nu,
               const float* __restrict__ x_std, const float* __restrict__ y_std,
               const float* __restrict__ W0, const float* __restrict__ b0,
               const float* __restrict__ b1, const float* __restrict__ b2,
               const float* __restrict__ b3, const float* __restrict__ W4,
               const unsigned short* __restrict__ wt, float* __restrict__ out)
{
    __shared__ unsigned short AH[7 * 16 * 256]; // 57344 B f16 activations (fragment order)
    __shared__ float w4_lds[256 * 4];           // 4 KB
    __shared__ float part_lds[8 * 6 * 16 * 4];  // 12 KB split-K partials
    __shared__ float y_lds[24 * 16];            // 1.5 KB

    const int tid = threadIdx.x;
    const int lane = tid & 63;
    const int wv = tid >> 6;     // wave 0..7
    const int l15 = lane & 15;
    const int g = lane >> 4;     // 0..3
    const int base_pt = blockIdx.x * NPTS_WG;

    if (tid < 256) ((float4*)w4_lds)[tid] = ((const float4*)W4)[tid];

    // ---- layer 0: 3 -> 256 dual seed ----
    {
        const int p = tid >> 5;            // 0..15
        const int j8 = (tid & 31) * 8;
        const float x0 = x_norm[(base_pt + p) * 3 + 0];
        const float x1 = x_norm[(base_pt + p) * 3 + 1];
        const float x2 = x_norm[(base_pt + p) * 3 + 2];
        float w0r[8], w1r[8], w2r[8], b0r[8];
        *(float4*)&w0r[0] = *(const float4*)&W0[0 * 256 + j8];
        *(float4*)&w0r[4] = *(const float4*)&W0[0 * 256 + j8 + 4];
        *(float4*)&w1r[0] = *(const float4*)&W0[1 * 256 + j8];
        *(float4*)&w1r[4] = *(const float4*)&W0[1 * 256 + j8 + 4];
        *(float4*)&w2r[0] = *(const float4*)&W0[2 * 256 + j8];
        *(float4*)&w2r[4] = *(const float4*)&W0[2 * 256 + j8 + 4];
        *(float4*)&b0r[0] = *(const float4*)&b0[j8];
        *(float4*)&b0r[4] = *(const float4*)&b0[j8 + 4];
        union { unsigned short u[8]; half8v v; } hv[7];
#pragma unroll
        for (int e = 0; e < 8; ++e) {
            const float z = b0r[e] + x0 * w0r[e] + x1 * w1r[e] + x2 * w2r[e];
            const float t = fast_tanh(z);
            const float s = 1.f - t * t;
            hv[0].u[e] = f16b(t);
            const float wvv[3] = {w0r[e], w1r[e], w2r[e]};
#pragma unroll
            for (int i = 0; i < 3; ++i) {
                hv[1 + i].u[e] = f16b(s * wvv[i]);
                hv[4 + i].u[e] = f16b(-2.f * t * s * wvv[i] * wvv[i]);
            }
        }
#pragma unroll
        for (int c = 0; c < 7; ++c)
            *(half8v*)&AH[aidx16(c, p, j8)] = hv[c].v;  // j8 8-aligned: one granule
    }
    __syncthreads();

    // ---- layers 1..3: swapped-operand MFMA: D[j][p] = W x A ----
    const float* biases[3] = {b1, b2, b3};
#pragma unroll 1
    for (int L = 0; L < 3; ++L) {
        const unsigned short* wtL = wt + (size_t)L * 131072;
        float4v acc[7][2];
#pragma unroll
        for (int c = 0; c < 7; ++c)
#pragma unroll
            for (int jt = 0; jt < 2; ++jt) acc[c][jt] = (float4v){0.f, 0.f, 0.f, 0.f};

        const unsigned short* bp0 = wtL + (wv * 32 + l15) * 256;        // jt=0 hi
        const unsigned short* bp1 = wtL + (wv * 32 + 16 + l15) * 256;   // jt=1 hi

        half8v bh0, bh1, bl0, bl1;
        {
            const int k0 = 8 * g;
            bh0 = *(const half8v*)(bp0 + k0);
            bh1 = *(const half8v*)(bp1 + k0);
            bl0 = *(const half8v*)(bp0 + 65536 + k0);
            bl1 = *(const half8v*)(bp1 + 65536 + k0);
        }
#pragma unroll
        for (int ks = 0; ks < 8; ++ks) {
            const int koct = ks * 32 + 8 * g;
            half8v nbh0, nbh1, nbl0, nbl1;
            if (ks < 7) {
                const int nk = koct + 32;
                nbh0 = *(const half8v*)(bp0 + nk);
                nbh1 = *(const half8v*)(bp1 + nk);
                nbl0 = *(const half8v*)(bp0 + 65536 + nk);
                nbl1 = *(const half8v*)(bp1 + 65536 + nk);
            }
#pragma unroll
            for (int c = 0; c < 7; ++c) {
                const half8v ah = *(const half8v*)&AH[aidx16(c, l15, koct)];
                acc[c][0] = __builtin_amdgcn_mfma_f32_16x16x32_f16(bh0, ah, acc[c][0], 0, 0, 0);
                acc[c][1] = __builtin_amdgcn_mfma_f32_16x16x32_f16(bh1, ah, acc[c][1], 0, 0, 0);
                if (c < 4) {  // d2 channels (4..6): hi-product only (nu-damped 100x)
                    acc[c][0] = __builtin_amdgcn_mfma_f32_16x16x32_f16(bl0, ah, acc[c][0], 0, 0, 0);
                    acc[c][1] = __builtin_amdgcn_mfma_f32_16x16x32_f16(bl1, ah, acc[c][1], 0, 0, 0);
                }
            }
            if (ks < 7) { bh0 = nbh0; bh1 = nbh1; bl0 = nbl0; bl1 = nbl1; }
        }
        const float* bL = biases[L];
        float bj[2][4];
        *(float4*)&bj[0][0] = *(const float4*)&bL[wv * 32 + 4 * g];
        *(float4*)&bj[1][0] = *(const float4*)&bL[wv * 32 + 16 + 4 * g];
        __syncthreads();   // all reads of A done before overwrite
#pragma unroll
        for (int jt = 0; jt < 2; ++jt) {
            const int jb = wv * 32 + jt * 16 + 4 * g;   // 4-aligned j-run base
            float val[7][4];
#pragma unroll
            for (int r = 0; r < 4; ++r) {
                const float z = acc[0][jt][r] + bj[jt][r];
                const float t = fast_tanh(z);
                const float s = 1.f - t * t;
                val[0][r] = t;
#pragma unroll
                for (int i = 0; i < 3; ++i) {
                    const float d1 = acc[1 + i][jt][r];
                    const float d2 = acc[4 + i][jt][r];
                    val[1 + i][r] = s * d1;
                    val[4 + i][r] = s * d2 - 2.f * t * s * d1 * d1;
                }
            }
            const int gr = jb >> 3, off = jb & 7;
#pragma unroll
            for (int c = 0; c < 7; ++c) {
                const uint32_t u0 = pk2f16(val[c][0], val[c][1]);
                const uint32_t u1 = pk2f16(val[c][2], val[c][3]);
                *(uint2*)&AH[((c * 16 + l15) << 8) + ((gr ^ l15) << 3) + off] =
                    make_uint2(u0, u1);   // one ds_write_b64, 8B-aligned
            }
        }
        __syncthreads();
    }

    // ---- layer 4: 256 -> 4, split-K across waves (wave = k-slice), swapped ----
    {
        const int koct = wv * 32 + 8 * g;
        union { uint32_t u[4]; half8v v; } HB, LB;
#pragma unroll
        for (int i = 0; i < 4; ++i) {
            const float w0v = (l15 < 4) ? w4_lds[(koct + 2 * i) * 4 + l15] : 0.f;
            const float w1v = (l15 < 4) ? w4_lds[(koct + 2 * i + 1) * 4 + l15] : 0.f;
            const unsigned short h0 = f16b(w0v), h1 = f16b(w1v);
            const float r0 = w0v - (float)__builtin_bit_cast(_Float16, h0);
            const float r1 = w1v - (float)__builtin_bit_cast(_Float16, h1);
            HB.u[i] = (uint32_t)h0 | ((uint32_t)h1 << 16);
            LB.u[i] = (uint32_t)f16b(r0) | ((uint32_t)f16b(r1) << 16);
        }
        float4v acc4[6];
#pragma unroll
        for (int c = 0; c < 6; ++c) acc4[c] = (float4v){0.f, 0.f, 0.f, 0.f};
#pragma unroll
        for (int c = 0; c < 6; ++c) {
            const half8v ah = *(const half8v*)&AH[aidx16(1 + c, l15, koct)];
            acc4[c] = __builtin_amdgcn_mfma_f32_16x16x32_f16(HB.v, ah, acc4[c], 0, 0, 0);
            if (c < 3)
                acc4[c] = __builtin_amdgcn_mfma_f32_16x16x32_f16(LB.v, ah, acc4[c], 0, 0, 0);
        }
        if (g == 0) {   // rows 0..3 = outputs u,v,w,p for point l15
#pragma unroll
            for (int c = 0; c < 6; ++c)
                *(float4*)&part_lds[((wv * 6 + c) * 16 + l15) * 4] =
                    make_float4(acc4[c][0], acc4[c][1], acc4[c][2], acc4[c][3]);
        }
    }
    __syncthreads();

    if (tid < 384) {          // reduce split-K partials + de-normalization scale
        const int p = tid & 15;
        const int co = tid >> 4;      // 0..23
        const int o = co & 3;
        const int c6 = co >> 2;       // 0..5: 0-2 = d1_i, 3-5 = d2_i
        float sum = 0.f;
#pragma unroll
        for (int w8 = 0; w8 < 8; ++w8) sum += part_lds[((w8 * 6 + c6) * 16 + p) * 4 + o];
        const int i = (c6 < 3) ? c6 : (c6 - 3);
        const float xs = x_std[i];
        const float scale = y_std[o] / ((c6 < 3) ? xs : (xs * xs));
        y_lds[co * 16 + p] = sum * scale;
    }
    __syncthreads();

    if (tid < 16) {           // physics loss per point
        const int p = tid;
        const float nuv = nu[0];
        #define YV(c6, o) y_lds[(((c6) * 4) + (o)) * 16 + p]
        const float cont = YV(0, 0) + YV(1, 1) + YV(2, 2);
        const float lap0 = YV(3, 0) + YV(4, 0) + YV(5, 0);
        const float lap1 = YV(3, 1) + YV(4, 1) + YV(5, 1);
        const float lap2 = YV(3, 2) + YV(4, 2) + YV(5, 2);
        const float mx = YV(0, 3) - nuv * lap0;
        const float my = YV(1, 3) - nuv * lap1;
        const float mz = YV(2, 3) - nuv * lap2;
        out[base_pt + p] = cont * cont + mx * mx + my * my + mz * mz;
        #undef YV
    }
}

extern "C" void kernel_launch(void* const* d_in, const int* in_sizes, int n_in,
                              void* d_out, int out_size, void* d_ws, size_t ws_size,
                              hipStream_t stream)
{
    const float* x_norm = (const float*)d_in[0];
    const float* nu     = (const float*)d_in[1];
    const float* x_std  = (const float*)d_in[2];
    const float* y_std  = (const float*)d_in[3];
    const float* W0 = (const float*)d_in[4];  const float* b0 = (const float*)d_in[5];
    const float* W1 = (const float*)d_in[6];  const float* b1 = (const float*)d_in[7];
    const float* W2 = (const float*)d_in[8];  const float* b2 = (const float*)d_in[9];
    const float* W3 = (const float*)d_in[10]; const float* b3 = (const float*)d_in[11];
    const float* W4 = (const float*)d_in[12];
    (void)n_in; (void)out_size; (void)ws_size;
    unsigned short* wt = (unsigned short*)d_ws;   // 786432 B
    float* out = (float*)d_out;
    const int npts = in_sizes[0] / 3;

    wt_split_kernel<<<48, 256, 0, stream>>>(W1, W2, W3, wt);
    pinn_mfma<<<npts / NPTS_WG, 512, 0, stream>>>(x_norm, nu, x_std, y_std,
        W0, b0, b1, b2, b3, W4, wt, out);
}